// Round 7
// baseline (227.115 us; speedup 1.0000x reference)
//
#include <hip/hip_runtime.h>
#include <math.h>

// VectorQuantizer, MFMA filter + exact-fp32 rescore.  N=32768 rows x K=8192
// codes, dim 64.
//
// R11 = R10b with BRANCH-FREE emission inside the MFMA loop.
//   R10b post-mortem: atomics removed, VGPR 52, 146us — but refit gives
//   ~205 cyc/candidate with ZERO atomics.  The remaining cost is control
//   flow: 64 v_cmp+s_cbranch sites per phase inside the MFMA loop are
//   scheduler barriers — the compiler can't pipeline the next ds_read/MFMA
//   past them (sweep A, branch-free fmax, pipelines fine; its phases are
//   ~2x cheaper).  Fix: per-thread 32-bit predicate mask per rt, built
//   arithmetically (m = (m<<1) | (d[r]>=thr), no branches, hides under
//   MFMA latency), ONE ballot-compaction per rt at PHASE END (2 uniform
//   sites/phase vs 64).  Entry = uint2{mask, lane|rt<<6|ch<<7}; rescore
//   expands set bits (bit b -> cell 31-b = t*4+r).  E~1.2 cands/entry,
//   ~210 entries/wave, CAP_W=512 (>20 sigma).  LDS ~34KB -> 4 blocks/CU.
//   Everything else identical to R10b (passed, absmax 0).
//
// Exact pipeline: S = sequential __fmaf_rn chain c=0..63; normx = numpy
// pairwise(n=64); d = fl(normx - 2S); (d_bits<<13|k) u64 atomicMin =
// value-then-lowest-index; 4 k-quarters merge in vq_out.

#define DIM      64
#define NCODE    8192
#define NROWS    32768
#define RPB      128               // rows per block: 4 waves x 2 row-tiles x 16
#define KQ       2048              // codes per block (gridDim.y = 4)
#define CHUNK    128               // codes staged in LDS at a time (16 KB)
#define NCHUNK   (KQ / CHUNK)      // 16
#define SEED_CH  2                 // seed chunks (256 codes) for the threshold
#define HALF_DELTA 4.0e-5f
#define CAP_W    512               // per-wave entry cap (expected ~210)

typedef __attribute__((ext_vector_type(8))) short frag8;   // 8 bf16
typedef __attribute__((ext_vector_type(4))) float f32x4;

__device__ __forceinline__ unsigned short f2bf_rne(float f) {
  unsigned u = __float_as_uint(f);
  return (unsigned short)((u + 0x7FFFu + ((u >> 16) & 1u)) >> 16);
}

// ---- kernel 0a: x [32][64][1024] -> xT [32768][64] (bit-copy transpose) ----
__global__ __launch_bounds__(256) void xpose(const float* __restrict__ x,
                                             float* __restrict__ xT) {
  __shared__ float t[64][65];                  // +1 pad: conflict-free
  const int b = blockIdx.x >> 4, hw0 = (blockIdx.x & 15) << 6;
  const float* xb = x + (size_t)b * (DIM * 1024) + hw0;
  const int r = threadIdx.x & 63, c0 = threadIdx.x >> 6;   // 4 c's per pass
#pragma unroll
  for (int cc = 0; cc < DIM; cc += 4)
    t[r][cc + c0] = xb[(size_t)(cc + c0) * 1024 + r];      // coalesced reads
  __syncthreads();
  float* o = xT + (size_t)(b * 1024 + hw0) * DIM;
#pragma unroll
  for (int it = 0; it < 4; ++it) {
    const int idx = it * 256 + threadIdx.x;                // 0..1023
    const int row = idx >> 4, j = (idx & 15) << 2;
    float4 v = {t[row][j], t[row][j + 1], t[row][j + 2], t[row][j + 3]};
    *(float4*)(o + row * DIM + j) = v;                     // contiguous writes
  }
}

// ---- kernel 0b: codebook fp32 -> bf16 (RNE), 8192x64 = 1 MB in ws ----
__global__ __launch_bounds__(256) void cvt_emb(const float* __restrict__ emb,
                                               unsigned short* __restrict__ ebf) {
  const int i = (blockIdx.x * 256 + threadIdx.x) * 8;
  const float4 a = *(const float4*)(emb + i);
  const float4 c = *(const float4*)(emb + i + 4);
  union { unsigned short u[8]; uint4 v; } o;
  o.u[0] = f2bf_rne(a.x); o.u[1] = f2bf_rne(a.y);
  o.u[2] = f2bf_rne(a.z); o.u[3] = f2bf_rne(a.w);
  o.u[4] = f2bf_rne(c.x); o.u[5] = f2bf_rne(c.y);
  o.u[6] = f2bf_rne(c.z); o.u[7] = f2bf_rne(c.w);
  *(uint4*)(ebf + i) = o.v;
}

// ---- kernel 1: per (128-row group, 2048-code quarter) ----
__global__ __launch_bounds__(256) void vq_main(
    const float* __restrict__ x, const float* __restrict__ emb,
    const unsigned short* __restrict__ ebf, const float* __restrict__ xT,
    unsigned long long* __restrict__ wsbest)
{
  __shared__ uint4 ldsB[CHUNK * 8];            // 16 KB bf16 codes (16B units)
  __shared__ float s_normx[RPB];
  __shared__ unsigned long long s_best[RPB];
  __shared__ uint2 s_candw[4][CAP_W];          // per-wave: {mask, lane|rt|ch}

  const int tid  = threadIdx.x;
  const int lane = tid & 63;
  const int wave = tid >> 6;
  const int s    = lane & 15;                  // MFMA m / n index
  const int q    = lane >> 4;                  // MFMA quad
  const int rowbase = blockIdx.x * RPB;
  const int kbase   = blockIdx.y * KQ;
  const int b    = rowbase >> 10;
  const int hw0  = rowbase & 1023;             // <= 896, block stays in one b
  const float* xb = x + (size_t)b * (DIM * 1024);

  // normx for row rowbase+tid (tid<128) — numpy pairwise_sum(n=64), bit-exact
  if (tid < RPB) {
    s_best[tid] = ~0ull;
    float p[DIM];
#pragma unroll
    for (int c = 0; c < DIM; ++c) {
      const float v = xb[(size_t)c * 1024 + hw0 + tid];
      p[c] = __fmul_rn(v, v);
    }
    float r8[8];
#pragma unroll
    for (int j = 0; j < 8; ++j) {
      float ss = p[j];
#pragma unroll
      for (int m = 1; m < 8; ++m) ss = __fadd_rn(ss, p[m * 8 + j]);
      r8[j] = ss;
    }
    const float t0 = __fadd_rn(r8[0], r8[1]), t1 = __fadd_rn(r8[2], r8[3]);
    const float t2 = __fadd_rn(r8[4], r8[5]), t3 = __fadd_rn(r8[6], r8[7]);
    s_normx[tid] = __fadd_rn(__fadd_rn(t0, t1), __fadd_rn(t2, t3));
  }

  // A-frags: wave owns 32 rows = 2 row-tiles of 16.  A[m=s][k=q*8+j].
  frag8 afr[2][2];
#pragma unroll
  for (int rt = 0; rt < 2; ++rt) {
    const float* xp = xb + hw0 + wave * 32 + rt * 16 + s;
#pragma unroll
    for (int h = 0; h < 2; ++h) {
      frag8 f;
#pragma unroll
      for (int j = 0; j < 8; ++j)
        f[j] = (short)f2bf_rne(xp[(size_t)(h * 32 + q * 8 + j) * 1024]);
      afr[rt][h] = f;
    }
  }

  // LDS B layout: slot code*8 + (j ^ (code&7)) holds 16B chunk j of code.
  // Frag read (code = t*16+s): lbA -> chunk q (c 0..31), lbB -> chunk 4+q.
  const int lbA = s * 8 + ((q)     ^ (s & 7));
  const int lbB = s * 8 + ((4 + q) ^ (s & 7));
  const frag8* ldsF = (const frag8*)ldsB;

  // ---- sweep A (seed): per-row max of S~ over the first SEED_CH chunks ----
  f32x4 smax[2];
#pragma unroll
  for (int rt = 0; rt < 2; ++rt) smax[rt] = (f32x4){-1e30f, -1e30f, -1e30f, -1e30f};

#pragma unroll 1
  for (int ch = 0; ch < SEED_CH; ++ch) {
    __syncthreads();
    {
      const int code = tid >> 1, half = tid & 1;   // 2 threads per code, 64B each
      const uint4* src = (const uint4*)(ebf + (size_t)(kbase + ch * CHUNK + code) * DIM) + half * 4;
      const int sw = code & 7;
#pragma unroll
      for (int j = 0; j < 4; ++j) ldsB[code * 8 + ((half * 4 + j) ^ sw)] = src[j];
    }
    __syncthreads();
#pragma unroll
    for (int t = 0; t < 8; ++t) {
      const frag8 b0 = ldsF[lbA + t * 128];
      const frag8 b1 = ldsF[lbB + t * 128];
#pragma unroll
      for (int rt = 0; rt < 2; ++rt) {
        f32x4 d = {0.f, 0.f, 0.f, 0.f};
        d = __builtin_amdgcn_mfma_f32_16x16x32_bf16(afr[rt][0], b0, d, 0, 0, 0);
        d = __builtin_amdgcn_mfma_f32_16x16x32_bf16(afr[rt][1], b1, d, 0, 0, 0);
        smax[rt][0] = fmaxf(smax[rt][0], d[0]);
        smax[rt][1] = fmaxf(smax[rt][1], d[1]);
        smax[rt][2] = fmaxf(smax[rt][2], d[2]);
        smax[rt][3] = fmaxf(smax[rt][3], d[3]);
      }
    }
  }

  // butterfly over the 16 code-columns: row q*4+r is s-independent, so after
  // xor{1,2,4,8} EVERY lane holds its row's seed max — no LDS round trip.
  float thr[2][4];
#pragma unroll
  for (int rt = 0; rt < 2; ++rt)
#pragma unroll
    for (int r = 0; r < 4; ++r) {
      float v = smax[rt][r];
      v = fmaxf(v, __shfl_xor(v, 1, 64));
      v = fmaxf(v, __shfl_xor(v, 2, 64));
      v = fmaxf(v, __shfl_xor(v, 4, 64));
      v = fmaxf(v, __shfl_xor(v, 8, 64));
      thr[rt][r] = v - HALF_DELTA;
    }

  // ---- sweep B: branch-free mask build, phase-end ballot compaction ----
  int wcnt = 0;                                // wave-uniform (SGPR)
  for (int ch = 0; ch < NCHUNK; ++ch) {
    __syncthreads();
    {
      const int code = tid >> 1, half = tid & 1;
      const uint4* src = (const uint4*)(ebf + (size_t)(kbase + ch * CHUNK + code) * DIM) + half * 4;
      const int sw = code & 7;
#pragma unroll
      for (int j = 0; j < 4; ++j) ldsB[code * 8 + ((half * 4 + j) ^ sw)] = src[j];
    }
    __syncthreads();
    unsigned m0 = 0u, m1 = 0u;                 // bit 31-(t*4+r) = cell (t,r)
#pragma unroll
    for (int t = 0; t < 8; ++t) {
      const frag8 b0 = ldsF[lbA + t * 128];
      const frag8 b1 = ldsF[lbB + t * 128];
      f32x4 d0 = {0.f, 0.f, 0.f, 0.f};
      d0 = __builtin_amdgcn_mfma_f32_16x16x32_bf16(afr[0][0], b0, d0, 0, 0, 0);
      d0 = __builtin_amdgcn_mfma_f32_16x16x32_bf16(afr[0][1], b1, d0, 0, 0, 0);
      f32x4 d1 = {0.f, 0.f, 0.f, 0.f};
      d1 = __builtin_amdgcn_mfma_f32_16x16x32_bf16(afr[1][0], b0, d1, 0, 0, 0);
      d1 = __builtin_amdgcn_mfma_f32_16x16x32_bf16(afr[1][1], b1, d1, 0, 0, 0);
      m0 = (m0 << 1) | (unsigned)(d0[0] >= thr[0][0]);
      m0 = (m0 << 1) | (unsigned)(d0[1] >= thr[0][1]);
      m0 = (m0 << 1) | (unsigned)(d0[2] >= thr[0][2]);
      m0 = (m0 << 1) | (unsigned)(d0[3] >= thr[0][3]);
      m1 = (m1 << 1) | (unsigned)(d1[0] >= thr[1][0]);
      m1 = (m1 << 1) | (unsigned)(d1[1] >= thr[1][1]);
      m1 = (m1 << 1) | (unsigned)(d1[2] >= thr[1][2]);
      m1 = (m1 << 1) | (unsigned)(d1[3] >= thr[1][3]);
    }
    // phase-end emission: 2 wave-uniform sites, outside the MFMA loop
#pragma unroll
    for (int rt = 0; rt < 2; ++rt) {
      const unsigned mm = rt ? m1 : m0;
      const unsigned long long bal = __ballot(mm != 0u);
      if (bal) {
        const int off = __builtin_amdgcn_mbcnt_hi(
            (unsigned)(bal >> 32),
            __builtin_amdgcn_mbcnt_lo((unsigned)bal, 0u));
        if (mm) {
          const int pos = wcnt + off;
          if (pos < CAP_W)
            s_candw[wave][pos] =
                (uint2){mm, (unsigned)(lane | (rt << 6) | (ch << 7))};
        }
        wcnt += __builtin_popcountll(bal);
      }
    }
  }

  // ---- exact rescore: expand entries, each wave rescores its own rows ----
  const int wc = min(wcnt, CAP_W);
  for (int i = lane; i < wc; i += 64) {
    const uint2 e = s_candw[wave][i];
    unsigned mm = e.x;
    const int elane = (int)(e.y & 63u);
    const int ert   = (int)((e.y >> 6) & 1u);
    const int ech   = (int)(e.y >> 7);
    const int es = elane & 15, eq = elane >> 4;
    while (mm) {
      const int bpos = 31 - __builtin_clz(mm);
      mm &= ~(1u << bpos);
      const int cell = 31 - bpos;              // t*4 + r
      const int t = cell >> 2, r = cell & 3;
      const int row_l = wave * 32 + ert * 16 + eq * 4 + r;
      const int kg = kbase + ech * CHUNK + t * 16 + es;
      const float* ep = emb + (size_t)kg * DIM;
      const float* xp = xT + (size_t)(rowbase + row_l) * DIM;
      float S = 0.f;
#pragma unroll
      for (int c = 0; c < DIM; ++c) S = __fmaf_rn(xp[c], ep[c], S);
      const float dd = __fsub_rn(s_normx[row_l], __fadd_rn(S, S));
      const unsigned long long pack =
          ((unsigned long long)__float_as_uint(dd) << 13) | (unsigned long long)kg;
      atomicMin(&s_best[row_l], pack);
    }
  }
  __syncthreads();

  if (tid < RPB)
    wsbest[(size_t)(rowbase + tid) * 4 + blockIdx.y] = s_best[tid];
}

// ---- kernel 2: merge quarters, write indices + gather z_q ----
__global__ __launch_bounds__(256) void vq_out(
    const float* __restrict__ emb, const unsigned long long* __restrict__ wsbest,
    float* __restrict__ zq, float* __restrict__ idx_out)
{
  const int row = blockIdx.x * 256 + threadIdx.x;
  unsigned long long p = wsbest[(size_t)row * 4];
#pragma unroll
  for (int j = 1; j < 4; ++j) {
    const unsigned long long pj = wsbest[(size_t)row * 4 + j];
    if (pj < p) p = pj;                        // d-major, then lowest k
  }
  const int k = (int)(p & 0x1FFFull);
  idx_out[row] = (float)k;
  const int b = row >> 10, hw = row & 1023;
  const float* ep = emb + (size_t)k * DIM;
  float* zp = zq + (size_t)b * (DIM * 1024) + hw;
#pragma unroll
  for (int c = 0; c < DIM; ++c) zp[(size_t)c * 1024] = ep[c];
}

extern "C" void kernel_launch(void* const* d_in, const int* in_sizes, int n_in,
                              void* d_out, int out_size, void* d_ws, size_t ws_size,
                              hipStream_t stream) {
  const float* x   = (const float*)d_in[0];   // [32, 64, 32, 32] fp32
  const float* emb = (const float*)d_in[1];   // [8192, 64] fp32

  float* zq      = (float*)d_out;
  float* idx_out = zq + (size_t)NROWS * DIM;

  unsigned short*     ebf    = (unsigned short*)d_ws;                          // 1 MB
  unsigned long long* wsbest = (unsigned long long*)((char*)d_ws + (1 << 20)); // 1 MB

  // xT (8 MB) borrows the zq output region; vq_out fully overwrites it later
  // and never reads zq, so this is stream-order safe with zero ws growth.
  float* xT = zq;

  xpose<<<dim3(512), 256, 0, stream>>>(x, xT);
  cvt_emb<<<dim3(256), 256, 0, stream>>>(emb, ebf);
  vq_main<<<dim3(NROWS / RPB, 4), 256, 0, stream>>>(x, emb, ebf, xT, wsbest);
  vq_out<<<dim3(NROWS / 256), 256, 0, stream>>>(emb, wsbest, zq, idx_out);
}

// Round 8
// 225.907 us; speedup vs baseline: 1.0053x; 1.0053x over previous
//
#include <hip/hip_runtime.h>
#include <math.h>

// VectorQuantizer, MFMA filter + exact-fp32 rescore.  N=32768 rows x K=8192
// codes, dim 64.
//
// R12 = R10b base (best: 146us vq_main) + rescore-bucket fixes.
//   R11 post-mortem: branch-free masks cost VGPR 52->92, occupancy 36->21,
//   net regression -> sweep-B structure stays R10b's.  The ~185cyc/cand
//   residual (190k cyc) is the RESCORE GATHER: per candidate 128 scalar
//   loads whose wave-instructions each touch 64 distinct cache lines
//   (address-divergence cost, scales per candidate; R9's xT fix halved it
//   by fixing only the x side).  Fixes:
//   1. float4 rescore loads (16 dwordx4 per operand vs 64 dword) — the
//      sequential __fmaf_rn chain order c=0..63 is preserved exactly.
//   2. running threshold: sweep B keeps fmax-ing smax (branch-free, like
//      sweep A) and refreshes thr by butterfly at each PHASE END.  A
//      prefix-max threshold is still a guaranteed superset (S~(k*) >=
//      max over ANY subset - HALF_DELTA), so the exact rescore fixes the
//      rest.  E[cands/row]: 1792/257~7 -> ln8~2.1 + band -> ~2.5x fewer.
//   3. xpose+cvt_emb fused into one prep kernel (one fewer launch).
//
// Exact pipeline: S = sequential __fmaf_rn chain c=0..63; normx = numpy
// pairwise(n=64); d = fl(normx - 2S); (d_bits<<13|k) u64 atomicMin =
// value-then-lowest-index; 4 k-quarters merge in vq_out.

#define DIM      64
#define NCODE    8192
#define NROWS    32768
#define RPB      128               // rows per block: 4 waves x 2 row-tiles x 16
#define KQ       2048              // codes per block (gridDim.y = 4)
#define CHUNK    128               // codes staged in LDS at a time (16 KB)
#define NCHUNK   (KQ / CHUNK)      // 16
#define SEED_CH  2                 // seed chunks (256 codes) for the threshold
#define HALF_DELTA 4.0e-5f
#define CAP_W    768               // per-wave candidate cap (expected ~130)

typedef __attribute__((ext_vector_type(8))) short frag8;   // 8 bf16
typedef __attribute__((ext_vector_type(4))) float f32x4;

__device__ __forceinline__ unsigned short f2bf_rne(float f) {
  unsigned u = __float_as_uint(f);
  return (unsigned short)((u + 0x7FFFu + ((u >> 16) & 1u)) >> 16);
}

// ---- kernel 0: fused prep.  All 512 blocks: x -> xT transpose tile.
//      Blocks 0..255 additionally: codebook fp32 -> bf16 (RNE). ----
__global__ __launch_bounds__(256) void prep(const float* __restrict__ x,
                                            float* __restrict__ xT,
                                            const float* __restrict__ emb,
                                            unsigned short* __restrict__ ebf) {
  if (blockIdx.x < 256) {
    const int i = (blockIdx.x * 256 + threadIdx.x) * 8;
    const float4 a = *(const float4*)(emb + i);
    const float4 c = *(const float4*)(emb + i + 4);
    union { unsigned short u[8]; uint4 v; } o;
    o.u[0] = f2bf_rne(a.x); o.u[1] = f2bf_rne(a.y);
    o.u[2] = f2bf_rne(a.z); o.u[3] = f2bf_rne(a.w);
    o.u[4] = f2bf_rne(c.x); o.u[5] = f2bf_rne(c.y);
    o.u[6] = f2bf_rne(c.z); o.u[7] = f2bf_rne(c.w);
    *(uint4*)(ebf + i) = o.v;
  }
  __shared__ float t[64][65];                  // +1 pad: conflict-free
  const int b = blockIdx.x >> 4, hw0 = (blockIdx.x & 15) << 6;
  const float* xb = x + (size_t)b * (DIM * 1024) + hw0;
  const int r = threadIdx.x & 63, c0 = threadIdx.x >> 6;   // 4 c's per pass
#pragma unroll
  for (int cc = 0; cc < DIM; cc += 4)
    t[r][cc + c0] = xb[(size_t)(cc + c0) * 1024 + r];      // coalesced reads
  __syncthreads();
  float* o = xT + (size_t)(b * 1024 + hw0) * DIM;
#pragma unroll
  for (int it = 0; it < 4; ++it) {
    const int idx = it * 256 + threadIdx.x;                // 0..1023
    const int row = idx >> 4, j = (idx & 15) << 2;
    float4 v = {t[row][j], t[row][j + 1], t[row][j + 2], t[row][j + 3]};
    *(float4*)(o + row * DIM + j) = v;                     // contiguous writes
  }
}

// ---- kernel 1: per (128-row group, 2048-code quarter) ----
__global__ __launch_bounds__(256) void vq_main(
    const float* __restrict__ x, const float* __restrict__ emb,
    const unsigned short* __restrict__ ebf, const float* __restrict__ xT,
    unsigned long long* __restrict__ wsbest)
{
  __shared__ uint4 ldsB[CHUNK * 8];            // 16 KB bf16 codes (16B units)
  __shared__ float s_normx[RPB];
  __shared__ unsigned long long s_best[RPB];
  __shared__ unsigned s_candw[4][CAP_W];       // per-wave: (row_in_wave<<11|kl)

  const int tid  = threadIdx.x;
  const int lane = tid & 63;
  const int wave = tid >> 6;
  const int s    = lane & 15;                  // MFMA m / n index
  const int q    = lane >> 4;                  // MFMA quad
  const int rowbase = blockIdx.x * RPB;
  const int kbase   = blockIdx.y * KQ;
  const int b    = rowbase >> 10;
  const int hw0  = rowbase & 1023;             // <= 896, block stays in one b
  const float* xb = x + (size_t)b * (DIM * 1024);

  // normx for row rowbase+tid (tid<128) — numpy pairwise_sum(n=64), bit-exact
  if (tid < RPB) {
    s_best[tid] = ~0ull;
    float p[DIM];
#pragma unroll
    for (int c = 0; c < DIM; ++c) {
      const float v = xb[(size_t)c * 1024 + hw0 + tid];
      p[c] = __fmul_rn(v, v);
    }
    float r8[8];
#pragma unroll
    for (int j = 0; j < 8; ++j) {
      float ss = p[j];
#pragma unroll
      for (int m = 1; m < 8; ++m) ss = __fadd_rn(ss, p[m * 8 + j]);
      r8[j] = ss;
    }
    const float t0 = __fadd_rn(r8[0], r8[1]), t1 = __fadd_rn(r8[2], r8[3]);
    const float t2 = __fadd_rn(r8[4], r8[5]), t3 = __fadd_rn(r8[6], r8[7]);
    s_normx[tid] = __fadd_rn(__fadd_rn(t0, t1), __fadd_rn(t2, t3));
  }

  // A-frags: wave owns 32 rows = 2 row-tiles of 16.  A[m=s][k=q*8+j].
  frag8 afr[2][2];
#pragma unroll
  for (int rt = 0; rt < 2; ++rt) {
    const float* xp = xb + hw0 + wave * 32 + rt * 16 + s;
#pragma unroll
    for (int h = 0; h < 2; ++h) {
      frag8 f;
#pragma unroll
      for (int j = 0; j < 8; ++j)
        f[j] = (short)f2bf_rne(xp[(size_t)(h * 32 + q * 8 + j) * 1024]);
      afr[rt][h] = f;
    }
  }

  // LDS B layout: slot code*8 + (j ^ (code&7)) holds 16B chunk j of code.
  // Frag read (code = t*16+s): lbA -> chunk q (c 0..31), lbB -> chunk 4+q.
  const int lbA = s * 8 + ((q)     ^ (s & 7));
  const int lbB = s * 8 + ((4 + q) ^ (s & 7));
  const frag8* ldsF = (const frag8*)ldsB;

  // ---- sweep A (seed): per-row max of S~ over the first SEED_CH chunks ----
  f32x4 smax[2];
#pragma unroll
  for (int rt = 0; rt < 2; ++rt) smax[rt] = (f32x4){-1e30f, -1e30f, -1e30f, -1e30f};

#pragma unroll 1
  for (int ch = 0; ch < SEED_CH; ++ch) {
    __syncthreads();
    {
      const int code = tid >> 1, half = tid & 1;   // 2 threads per code, 64B each
      const uint4* src = (const uint4*)(ebf + (size_t)(kbase + ch * CHUNK + code) * DIM) + half * 4;
      const int sw = code & 7;
#pragma unroll
      for (int j = 0; j < 4; ++j) ldsB[code * 8 + ((half * 4 + j) ^ sw)] = src[j];
    }
    __syncthreads();
#pragma unroll
    for (int t = 0; t < 8; ++t) {
      const frag8 b0 = ldsF[lbA + t * 128];
      const frag8 b1 = ldsF[lbB + t * 128];
#pragma unroll
      for (int rt = 0; rt < 2; ++rt) {
        f32x4 d = {0.f, 0.f, 0.f, 0.f};
        d = __builtin_amdgcn_mfma_f32_16x16x32_bf16(afr[rt][0], b0, d, 0, 0, 0);
        d = __builtin_amdgcn_mfma_f32_16x16x32_bf16(afr[rt][1], b1, d, 0, 0, 0);
        smax[rt][0] = fmaxf(smax[rt][0], d[0]);
        smax[rt][1] = fmaxf(smax[rt][1], d[1]);
        smax[rt][2] = fmaxf(smax[rt][2], d[2]);
        smax[rt][3] = fmaxf(smax[rt][3], d[3]);
      }
    }
  }

  // butterfly over the 16 code-columns: row q*4+r is s-independent, so after
  // xor{1,2,4,8} EVERY lane holds its row's seed max — no LDS round trip.
  float thr[2][4];
#pragma unroll
  for (int rt = 0; rt < 2; ++rt)
#pragma unroll
    for (int r = 0; r < 4; ++r) {
      float v = smax[rt][r];
      v = fmaxf(v, __shfl_xor(v, 1, 64));
      v = fmaxf(v, __shfl_xor(v, 2, 64));
      v = fmaxf(v, __shfl_xor(v, 4, 64));
      v = fmaxf(v, __shfl_xor(v, 8, 64));
      thr[rt][r] = v - HALF_DELTA;
    }

  // ---- sweep B: emit vs RUNNING prefix-max threshold (tightens per phase) --
  int wcnt = 0;                                // wave-uniform (SGPR)
  for (int ch = 0; ch < NCHUNK; ++ch) {
    __syncthreads();
    {
      const int code = tid >> 1, half = tid & 1;
      const uint4* src = (const uint4*)(ebf + (size_t)(kbase + ch * CHUNK + code) * DIM) + half * 4;
      const int sw = code & 7;
#pragma unroll
      for (int j = 0; j < 4; ++j) ldsB[code * 8 + ((half * 4 + j) ^ sw)] = src[j];
    }
    __syncthreads();
#pragma unroll
    for (int t = 0; t < 8; ++t) {
      const frag8 b0 = ldsF[lbA + t * 128];
      const frag8 b1 = ldsF[lbB + t * 128];
      const int kl = ch * CHUNK + t * 16 + s;
#pragma unroll
      for (int rt = 0; rt < 2; ++rt) {
        f32x4 d = {0.f, 0.f, 0.f, 0.f};
        d = __builtin_amdgcn_mfma_f32_16x16x32_bf16(afr[rt][0], b0, d, 0, 0, 0);
        d = __builtin_amdgcn_mfma_f32_16x16x32_bf16(afr[rt][1], b1, d, 0, 0, 0);
#pragma unroll
        for (int r = 0; r < 4; ++r) {
          const bool pr = d[r] >= thr[rt][r];
          const unsigned long long m = __ballot(pr);
          if (m) {                             // wave-uniform branch
            const int off = __builtin_amdgcn_mbcnt_hi(
                (unsigned)(m >> 32),
                __builtin_amdgcn_mbcnt_lo((unsigned)m, 0u));
            if (pr) {
              const int pos = wcnt + off;
              if (pos < CAP_W)
                s_candw[wave][pos] =
                    ((unsigned)(rt * 16 + q * 4 + r) << 11) | (unsigned)kl;
            }
            wcnt += __builtin_popcountll(m);
          }
        }
        // branch-free running max (hides under MFMA latency, like sweep A)
        smax[rt][0] = fmaxf(smax[rt][0], d[0]);
        smax[rt][1] = fmaxf(smax[rt][1], d[1]);
        smax[rt][2] = fmaxf(smax[rt][2], d[2]);
        smax[rt][3] = fmaxf(smax[rt][3], d[3]);
      }
    }
    // phase-end: tighten thr to (prefix max so far) - HALF_DELTA.  A
    // prefix-max threshold keeps the guaranteed-superset property.
#pragma unroll
    for (int rt = 0; rt < 2; ++rt)
#pragma unroll
      for (int r = 0; r < 4; ++r) {
        float v = smax[rt][r];
        v = fmaxf(v, __shfl_xor(v, 1, 64));
        v = fmaxf(v, __shfl_xor(v, 2, 64));
        v = fmaxf(v, __shfl_xor(v, 4, 64));
        v = fmaxf(v, __shfl_xor(v, 8, 64));
        thr[rt][r] = v - HALF_DELTA;
      }
  }

  // ---- exact rescore: each wave rescores its own candidates.
  //      float4 loads (4x fewer scattered-address instructions); the
  //      sequential __fmaf_rn chain order c=0..63 is preserved exactly. ----
  const int wc = min(wcnt, CAP_W);
  for (int i = lane; i < wc; i += 64) {
    const unsigned e = s_candw[wave][i];
    const int row_l = wave * 32 + (int)(e >> 11);
    const int kg = kbase + (int)(e & 0x7FFu);
    const float4* ep4 = (const float4*)(emb + (size_t)kg * DIM);
    const float4* xp4 = (const float4*)(xT + (size_t)(rowbase + row_l) * DIM);
    float S = 0.f;
#pragma unroll
    for (int c4 = 0; c4 < DIM / 4; ++c4) {
      const float4 e4 = ep4[c4];
      const float4 x4 = xp4[c4];
      S = __fmaf_rn(x4.x, e4.x, S);
      S = __fmaf_rn(x4.y, e4.y, S);
      S = __fmaf_rn(x4.z, e4.z, S);
      S = __fmaf_rn(x4.w, e4.w, S);
    }
    const float dd = __fsub_rn(s_normx[row_l], __fadd_rn(S, S));
    const unsigned long long pack =
        ((unsigned long long)__float_as_uint(dd) << 13) | (unsigned long long)kg;
    atomicMin(&s_best[row_l], pack);
  }
  __syncthreads();

  if (tid < RPB)
    wsbest[(size_t)(rowbase + tid) * 4 + blockIdx.y] = s_best[tid];
}

// ---- kernel 2: merge quarters, write indices + gather z_q ----
__global__ __launch_bounds__(256) void vq_out(
    const float* __restrict__ emb, const unsigned long long* __restrict__ wsbest,
    float* __restrict__ zq, float* __restrict__ idx_out)
{
  const int row = blockIdx.x * 256 + threadIdx.x;
  unsigned long long p = wsbest[(size_t)row * 4];
#pragma unroll
  for (int j = 1; j < 4; ++j) {
    const unsigned long long pj = wsbest[(size_t)row * 4 + j];
    if (pj < p) p = pj;                        // d-major, then lowest k
  }
  const int k = (int)(p & 0x1FFFull);
  idx_out[row] = (float)k;
  const int b = row >> 10, hw = row & 1023;
  const float* ep = emb + (size_t)k * DIM;
  float* zp = zq + (size_t)b * (DIM * 1024) + hw;
#pragma unroll
  for (int c = 0; c < DIM; ++c) zp[(size_t)c * 1024] = ep[c];
}

extern "C" void kernel_launch(void* const* d_in, const int* in_sizes, int n_in,
                              void* d_out, int out_size, void* d_ws, size_t ws_size,
                              hipStream_t stream) {
  const float* x   = (const float*)d_in[0];   // [32, 64, 32, 32] fp32
  const float* emb = (const float*)d_in[1];   // [8192, 64] fp32

  float* zq      = (float*)d_out;
  float* idx_out = zq + (size_t)NROWS * DIM;

  unsigned short*     ebf    = (unsigned short*)d_ws;                          // 1 MB
  unsigned long long* wsbest = (unsigned long long*)((char*)d_ws + (1 << 20)); // 1 MB

  // xT (8 MB) borrows the zq output region; vq_out fully overwrites it later
  // and never reads zq, so this is stream-order safe with zero ws growth.
  float* xT = zq;

  prep<<<dim3(512), 256, 0, stream>>>(x, xT, emb, ebf);
  vq_main<<<dim3(NROWS / RPB, 4), 256, 0, stream>>>(x, emb, ebf, xT, wsbest);
  vq_out<<<dim3(NROWS / 256), 256, 0, stream>>>(emb, wsbest, zq, idx_out);
}